// Round 8
// baseline (6875.533 us; speedup 1.0000x reference)
//
#include <hip/hip_runtime.h>

using u32 = unsigned int;
using u64 = unsigned long long;
using bf16x8 = __attribute__((ext_vector_type(8))) short;
using f32x4  = __attribute__((ext_vector_type(4))) float;

// Problem constants
#define BB_ 64
#define TT_ 512
#define II_ 1024
#define HH_ 1024
#define NSCAN_BLOCKS 64   // 4 groups (16 batch rows) x 16 blocks x 4 waves (16 cols/wave)

__device__ __forceinline__ unsigned short bf16rne(float f) {
  u32 u = __float_as_uint(f);
  return (unsigned short)((u + 0x7FFFu + ((u >> 16) & 1u)) >> 16);
}
__device__ __forceinline__ u32 pk2(float a, float b) {
  u32 ua = __float_as_uint(a), ub = __float_as_uint(b);
  u32 lo = (ua + 0x7FFFu + ((ua >> 16) & 1u)) >> 16;
  u32 hi = (ub + 0x7FFFu + ((ub >> 16) & 1u)) & 0xFFFF0000u;
  return lo | hi;
}
__device__ __forceinline__ void gll16(const void* g, void* s) {
  __builtin_amdgcn_global_load_lds(
      (const __attribute__((address_space(1))) u32*)g,
      (__attribute__((address_space(3))) u32*)s, 16, 0, 0);
}
// fast tanh: 1 - 2/(exp2(2*log2e*x)+1); |err| < 1e-6, exact +-1 saturation
__device__ __forceinline__ float tanhfast(float x) {
  float e = __builtin_amdgcn_exp2f(x * 2.885390081777927f);
  return 1.0f - 2.0f / (e + 1.0f);
}

__device__ __forceinline__ void cvt4(const float* __restrict__ s, unsigned short* __restrict__ d, long long g) {
  float4 v = ((const float4*)s)[g];
  ushort4 o;
  o.x = bf16rne(v.x); o.y = bf16rne(v.y); o.z = bf16rne(v.z); o.w = bf16rne(v.w);
  ((ushort4*)d)[g] = o;
}

// ---------------------------------------------------------------------------
// k_convert (r1-proven): bf16 copies of x / W_ih / [W_hh1;W_hh2],
// hbuf[parity0]=bf16(h0), flags (16KB) = 0. Replay-safe (full rewrite).
// ---------------------------------------------------------------------------
__global__ void k_convert(const float* __restrict__ x, const float* __restrict__ h0,
                          const float* __restrict__ Wih, const float* __restrict__ Wh1,
                          const float* __restrict__ Wh2,
                          unsigned short* __restrict__ xb, unsigned short* __restrict__ Wihb,
                          unsigned short* __restrict__ Wcatb, unsigned short* __restrict__ hbuf,
                          int* __restrict__ cnt, int do_x) {
  const long long NWI = (long long)HH_ * II_ / 4;
  const long long NH0 = (long long)BB_ * HH_ / 4;
  const long long NC  = 1024;  // 4096 flag u32s via int4 (16 KB)
  const long long NX  = do_x ? ((long long)BB_ * TT_ * II_ / 4) : 0;
  const long long total = 3 * NWI + NH0 + NC + NX;
  for (long long g = (long long)blockIdx.x * blockDim.x + threadIdx.x; g < total;
       g += (long long)gridDim.x * blockDim.x) {
    if (g < NWI) {
      cvt4(Wih, Wihb, g);
    } else if (g < 2 * NWI) {
      cvt4(Wh1, Wcatb, g - NWI);
    } else if (g < 3 * NWI) {
      cvt4(Wh2, Wcatb + (long long)HH_ * II_, g - 2 * NWI);
    } else if (g < 3 * NWI + NH0) {
      cvt4(h0, hbuf, g - 3 * NWI);
    } else if (g < 3 * NWI + NH0 + NC) {
      ((int4*)cnt)[g - 3 * NWI - NH0] = make_int4(0, 0, 0, 0);
    } else {
      cvt4(x, xb, g - (3 * NWI + NH0 + NC));
    }
  }
}

// ---------------------------------------------------------------------------
// k_gemm: xp = x @ Wih^T + b_ih, written into d_out. (unchanged, verified)
// ---------------------------------------------------------------------------
template <bool XB>
__global__ __launch_bounds__(256) void k_gemm(const unsigned short* __restrict__ xbg,
                                              const float* __restrict__ xf,
                                              const unsigned short* __restrict__ Wb,
                                              const float* __restrict__ bias,
                                              float* __restrict__ C) {
  __shared__ __align__(16) unsigned short ldsA[128 * 64];
  __shared__ __align__(16) unsigned short ldsB[128 * 64];
  const int tid = threadIdx.x;
  const int w = tid >> 6, l = tid & 63;
  const int lr = l & 15, lk = l >> 4;
  const int n0 = (blockIdx.x & 7) * 128;
  const int m0 = (blockIdx.x >> 3) * 128;
  const int mbase = (w >> 1) * 64, nbase = (w & 1) * 64;

  f32x4 acc[4][4] = {};

  for (int kb = 0; kb < 16; ++kb) {
    const int k0 = kb * 64;
#pragma unroll
    for (int r = 0; r < 4; ++r) {
      int tb = r * 4096 + w * 1024 + l * 16;
      int row = tb >> 7;
      int p = (tb >> 4) & 7;
      int c = p ^ (row & 7);
      gll16(Wb + (u64)(n0 + row) * II_ + k0 + c * 8,
            (char*)ldsB + r * 4096 + w * 1024);
    }
    if constexpr (XB) {
#pragma unroll
      for (int r = 0; r < 4; ++r) {
        int tb = r * 4096 + w * 1024 + l * 16;
        int row = tb >> 7;
        int p = (tb >> 4) & 7;
        int c = p ^ (row & 7);
        gll16(xbg + (u64)(m0 + row) * II_ + k0 + c * 8,
              (char*)ldsA + r * 4096 + w * 1024);
      }
    } else {
      const int r = tid >> 1, ch = tid & 1;
      const float* gs = xf + (u64)(m0 + r) * II_ + k0 + ch * 32;
      float4 v[8];
#pragma unroll
      for (int q = 0; q < 8; ++q) v[q] = ((const float4*)gs)[q];
#pragma unroll
      for (int q = 0; q < 4; ++q) {
        int c = ch * 4 + q;
        int p = c ^ (r & 7);
        uint4 pk;
        pk.x = pk2(v[2 * q].x, v[2 * q].y);
        pk.y = pk2(v[2 * q].z, v[2 * q].w);
        pk.z = pk2(v[2 * q + 1].x, v[2 * q + 1].y);
        pk.w = pk2(v[2 * q + 1].z, v[2 * q + 1].w);
        *(uint4*)((char*)ldsA + r * 128 + p * 16) = pk;
      }
    }
    __syncthreads();

    bf16x8 a[4][2], b[4][2];
#pragma unroll
    for (int mt = 0; mt < 4; ++mt) {
      int row = mbase + mt * 16 + lr;
#pragma unroll
      for (int kk = 0; kk < 2; ++kk) {
        int c = kk * 4 + lk, p = c ^ (row & 7);
        a[mt][kk] = *(const bf16x8*)((const char*)ldsA + row * 128 + p * 16);
      }
    }
#pragma unroll
    for (int nt = 0; nt < 4; ++nt) {
      int row = nbase + nt * 16 + lr;
#pragma unroll
      for (int kk = 0; kk < 2; ++kk) {
        int c = kk * 4 + lk, p = c ^ (row & 7);
        b[nt][kk] = *(const bf16x8*)((const char*)ldsB + row * 128 + p * 16);
      }
    }
#pragma unroll
    for (int kk = 0; kk < 2; ++kk)
#pragma unroll
      for (int mt = 0; mt < 4; ++mt)
#pragma unroll
        for (int nt = 0; nt < 4; ++nt)
          acc[mt][nt] = __builtin_amdgcn_mfma_f32_16x16x32_bf16(a[mt][kk], b[nt][kk], acc[mt][nt], 0, 0, 0);
    __syncthreads();
  }

  float bn[4];
#pragma unroll
  for (int nt = 0; nt < 4; ++nt) bn[nt] = bias[n0 + nbase + nt * 16 + lr];
#pragma unroll
  for (int mt = 0; mt < 4; ++mt) {
#pragma unroll
    for (int i = 0; i < 4; ++i) {
      int m = m0 + mbase + mt * 16 + lk * 4 + i;
      float* cr = C + (u64)m * HH_ + n0 + nbase + lr;
#pragma unroll
      for (int nt = 0; nt < 4; ++nt) cr[nt * 16] = acc[mt][nt][i] + bn[nt];
    }
  }
}

// ---------------------------------------------------------------------------
// k_scan v8: wave-autonomous scan, full-tile geometry.
// 64 blocks x 4 waves = 256 waves. Group g = blockIdx&3 owns batch rows
// [16g, 16g+16); each wave owns 16 h-cols (jbw) with FULL K=1024, both gates:
// wt[2][32] bf16x8 = 256 AGPRs, pinned via asm "a" constraints (r4-proven).
// Operand swap (algebra verified vs r1-r6 layouts): acc = mfma(A=W, B=h):
//   A[j_local=lane&15][k]  = W[jbw+lane&15][kk*32+(lane>>4)*8+e]
//   B[k][batch=lane&15]    = h[bb+lane&15][kk*32+(lane>>4)*8+e]
//   D[j_local=(lane>>4)*4+i][batch=lane&15]  -> gates lane-local,
//   one contiguous u64 h-store per lane (batch bb+lr, cols jbw+lk*4..+3).
// All 16 D cols real (16 batch rows/group) -> no zero-lanes, no cndmasks.
// Fixes vs r7: (1) per-kk h loads inside the MFMA loop (no qv[64] pressure;
// compiler inserts the vmcnt waits for each asm use - r6-proven pattern);
// (2) accs routed THROUGH the s_nop asm as "+v" in-outs so every gate read
// is data-ordered after the MFMA wait states.
// Protocol (r2/r6-proven): per-wave 32B-padded flags; producer h-stores
// (relaxed agent) -> vmcnt(0) -> lane0 RELEASE flag; consumer 64-lane flag
// poll then relaxed agent u64 h loads. Equality flags + double buffer.
// ---------------------------------------------------------------------------
__global__ __launch_bounds__(256, 1) void k_scan(float* __restrict__ out, const float* __restrict__ h0,
                                                 const float* __restrict__ b1, const float* __restrict__ b2,
                                                 const unsigned short* __restrict__ Wcat,
                                                 unsigned short* __restrict__ hbuf, u32* __restrict__ flags) {
  const int tid = threadIdx.x, wv = tid >> 6, l = tid & 63;
  const int lr = l & 15, lk = l >> 4;
  const int g = blockIdx.x & 3, r = blockIdx.x >> 2;   // r in 0..15
  const int bb = g * 16;             // 16 batch rows of this group
  const int jbw = r * 64 + wv * 16;  // this wave's 16 h-cols

  // --- weights -> 256 AGPRs: wt[nt][kk] = W[(nt?HH_:0)+jbw+lr][kk*32+lk*8..+8]
  bf16x8 wt[2][32];
#pragma unroll
  for (int nt = 0; nt < 2; ++nt) {
    const unsigned short* wr = Wcat + (u64)(nt * HH_ + jbw + lr) * HH_ + lk * 8;
#pragma unroll
    for (int kk = 0; kk < 32; ++kk) wt[nt][kk] = *(const bf16x8*)(wr + kk * 32);
  }

  // --- per-lane identity: batch row grow = bb+lr, cols col0 = jbw+lk*4..+3 ---
  const int grow = bb + lr;
  const int col0 = jbw + lk * 4;
  float b1v[4], b2v[4];
  f32x4 hold;
#pragma unroll
  for (int i = 0; i < 4; ++i) {
    b1v[i] = b1[col0 + i];
    b2v[i] = b2[col0 + i];
    hold[i] = h0[(u64)grow * HH_ + col0 + i];
  }
  float* outp = out + (u64)grow * TT_ * HH_ + col0;  // + t*HH_ per step

  u32* gflag = flags + g * 512;            // 64 flags, stride 8 u32 (32B)
  const int fidx = (r * 4 + wv) * 8;       // this wave's flag slot
  const u64 hldw = ((u64)grow * HH_ + lk * 8) >> 2;   // h-load base (u64 idx)
  const u64 hstw = ((u64)grow * HH_ + col0) >> 2;     // h-store slot (u64 idx)

  for (int t = 0; t < TT_; ++t) {
    float4 xpv = *(const float4*)(outp + (u64)t * HH_);  // hides under poll

    if (t > 0) {
      const u32 need = (u32)t;
      while (true) {
        u32 v = __hip_atomic_load(gflag + l * 8, __ATOMIC_RELAXED, __HIP_MEMORY_SCOPE_AGENT);
        if (__all((int)(v >= need))) break;
        __builtin_amdgcn_s_sleep(1);
      }
    }

    // --- full-K MFMA; h loaded per-kk (compiler-managed vmcnt waits) ---
    const u64* hB = (const u64*)hbuf + (u64)(t & 1) * (BB_ * HH_ / 4) + hldw;
    f32x4 acc0 = {}, acc1 = {};
#pragma unroll
    for (int kk = 0; kk < 32; ++kk) {
      union { u64 q[2]; bf16x8 v; } au;
      au.q[0] = __hip_atomic_load(hB + kk * 8,     __ATOMIC_RELAXED, __HIP_MEMORY_SCOPE_AGENT);
      au.q[1] = __hip_atomic_load(hB + kk * 8 + 1, __ATOMIC_RELAXED, __HIP_MEMORY_SCOPE_AGENT);
      asm("v_mfma_f32_16x16x32_bf16 %0, %1, %2, %0"
          : "+v"(acc0) : "a"(wt[0][kk]), "v"(au.v));
      asm("v_mfma_f32_16x16x32_bf16 %0, %1, %2, %0"
          : "+v"(acc1) : "a"(wt[1][kk]), "v"(au.v));
    }
    // Hazard fence: accs pass THROUGH this asm -> all consumer reads are
    // data-ordered after the MFMA wait states.
    asm volatile("s_nop 7\n\ts_nop 7\n\ts_nop 7" : "+v"(acc0), "+v"(acc1));

    // --- lane-local gates (4 outcols of one batch row) ---
    f32x4 hn;
#pragma unroll
    for (int i = 0; i < 4; ++i) {
      float xi = ((const float*)&xpv)[i];
      float t1 = tanhfast(acc0[i] + xi + b1v[i]);
      float t2 = tanhfast(acc1[i] + xi + b2v[i]);
      hn[i] = t1 + hold[i] * (t2 - t1);  // (1-h)*v1 + h*v2
    }
    hold = hn;

    // --- publish: one u64 h-store/lane, vmcnt(0), lane0 RELEASE flag ---
    if (t < TT_ - 1) {
      u32 lo = (u32)bf16rne(hn[0]) | ((u32)bf16rne(hn[1]) << 16);
      u32 hi = (u32)bf16rne(hn[2]) | ((u32)bf16rne(hn[3]) << 16);
      u64 wd = (u64)lo | ((u64)hi << 32);
      __hip_atomic_store((u64*)hbuf + (u64)((t + 1) & 1) * (BB_ * HH_ / 4) + hstw, wd,
                         __ATOMIC_RELAXED, __HIP_MEMORY_SCOPE_AGENT);
      asm volatile("s_waitcnt vmcnt(0)" ::: "memory");
      if (l == 0)
        __hip_atomic_store(gflag + fidx, (u32)(t + 1), __ATOMIC_RELEASE, __HIP_MEMORY_SCOPE_AGENT);
    }

    // --- trajectory + h_T stores (off the handshake path) ---
    *(float4*)(outp + (u64)t * HH_) = *(const float4*)&hn;
    if (t == TT_ - 1)
      *(float4*)(out + (u64)BB_ * TT_ * HH_ + (u64)grow * HH_ + col0) = *(const float4*)&hn;
  }
}

// ---------------------------------------------------------------------------
extern "C" void kernel_launch(void* const* d_in, const int* in_sizes, int n_in,
                              void* d_out, int out_size, void* d_ws, size_t ws_size,
                              hipStream_t stream) {
  const float* x    = (const float*)d_in[0];
  const float* h0   = (const float*)d_in[1];
  const float* Wih  = (const float*)d_in[2];
  const float* bih  = (const float*)d_in[3];
  const float* Whh1 = (const float*)d_in[4];
  const float* bhh1 = (const float*)d_in[5];
  const float* Whh2 = (const float*)d_in[6];
  const float* bhh2 = (const float*)d_in[7];
  float* out = (float*)d_out;

  char* ws = (char*)d_ws;
  unsigned short* Wihb  = (unsigned short*)(ws + 0);          //  2 MiB
  unsigned short* Wcatb = (unsigned short*)(ws + 2097152);    //  4 MiB
  unsigned short* hbuf  = (unsigned short*)(ws + 6291456);    //  256 KiB (2 bf16 buffers)
  int*            cnt   = (int*)(ws + 6553600);               //  16 KiB (padded wave flags)
  unsigned short* xb    = (unsigned short*)(ws + 6569984);    //  64 MiB
  const bool fastx = ws_size >= 73678848ULL;

  hipLaunchKernelGGL(k_convert, dim3(2048), dim3(256), 0, stream,
                     x, h0, Wih, Whh1, Whh2, xb, Wihb, Wcatb, hbuf, cnt, (int)fastx);
  if (fastx)
    hipLaunchKernelGGL((k_gemm<true>), dim3(2048), dim3(256), 0, stream,
                       xb, (const float*)nullptr, Wihb, bih, out);
  else
    hipLaunchKernelGGL((k_gemm<false>), dim3(2048), dim3(256), 0, stream,
                       (const unsigned short*)nullptr, x, Wihb, bih, out);
  hipLaunchKernelGGL(k_scan, dim3(NSCAN_BLOCKS), dim3(256), 0, stream,
                     out, h0, bhh1, bhh2, Wcatb, hbuf, (u32*)cnt);
}

// Round 9
// 2186.985 us; speedup vs baseline: 3.1438x; 3.1438x over previous
//
#include <hip/hip_runtime.h>

using u32 = unsigned int;
using u64 = unsigned long long;
using bf16x8 = __attribute__((ext_vector_type(8))) short;
using f32x4  = __attribute__((ext_vector_type(4))) float;

// Problem constants
#define BB_ 64
#define TT_ 512
#define II_ 1024
#define HH_ 1024
#define NSCAN_BLOCKS 128   // 4 domains (16 batch rows) x 32 j-blocks (32 cols)

__device__ __forceinline__ unsigned short bf16rne(float f) {
  u32 u = __float_as_uint(f);
  return (unsigned short)((u + 0x7FFFu + ((u >> 16) & 1u)) >> 16);
}
__device__ __forceinline__ u32 pk2(float a, float b) {
  u32 ua = __float_as_uint(a), ub = __float_as_uint(b);
  u32 lo = (ua + 0x7FFFu + ((ua >> 16) & 1u)) >> 16;
  u32 hi = (ub + 0x7FFFu + ((ub >> 16) & 1u)) & 0xFFFF0000u;
  return lo | hi;
}
__device__ __forceinline__ void gll16(const void* g, void* s) {
  __builtin_amdgcn_global_load_lds(
      (const __attribute__((address_space(1))) u32*)g,
      (__attribute__((address_space(3))) u32*)s, 16, 0, 0);
}
// fast tanh: 1 - 2/(exp2(2*log2e*x)+1); |err| < 1e-6, exact +-1 saturation
__device__ __forceinline__ float tanhfast(float x) {
  float e = __builtin_amdgcn_exp2f(x * 2.885390081777927f);
  return 1.0f - 2.0f / (e + 1.0f);
}

__device__ __forceinline__ void cvt4(const float* __restrict__ s, unsigned short* __restrict__ d, long long g) {
  float4 v = ((const float4*)s)[g];
  ushort4 o;
  o.x = bf16rne(v.x); o.y = bf16rne(v.y); o.z = bf16rne(v.z); o.w = bf16rne(v.w);
  ((ushort4*)d)[g] = o;
}

// ---------------------------------------------------------------------------
// k_convert (r1-proven): bf16 copies of x / W_ih / [W_hh1;W_hh2],
// hbuf[parity0]=bf16(h0), flags (16KB) = 0. Replay-safe (full rewrite).
// ---------------------------------------------------------------------------
__global__ void k_convert(const float* __restrict__ x, const float* __restrict__ h0,
                          const float* __restrict__ Wih, const float* __restrict__ Wh1,
                          const float* __restrict__ Wh2,
                          unsigned short* __restrict__ xb, unsigned short* __restrict__ Wihb,
                          unsigned short* __restrict__ Wcatb, unsigned short* __restrict__ hbuf,
                          int* __restrict__ cnt, int do_x) {
  const long long NWI = (long long)HH_ * II_ / 4;
  const long long NH0 = (long long)BB_ * HH_ / 4;
  const long long NC  = 1024;  // 4096 flag u32s via int4 (16 KB)
  const long long NX  = do_x ? ((long long)BB_ * TT_ * II_ / 4) : 0;
  const long long total = 3 * NWI + NH0 + NC + NX;
  for (long long g = (long long)blockIdx.x * blockDim.x + threadIdx.x; g < total;
       g += (long long)gridDim.x * blockDim.x) {
    if (g < NWI) {
      cvt4(Wih, Wihb, g);
    } else if (g < 2 * NWI) {
      cvt4(Wh1, Wcatb, g - NWI);
    } else if (g < 3 * NWI) {
      cvt4(Wh2, Wcatb + (long long)HH_ * II_, g - 2 * NWI);
    } else if (g < 3 * NWI + NH0) {
      cvt4(h0, hbuf, g - 3 * NWI);
    } else if (g < 3 * NWI + NH0 + NC) {
      ((int4*)cnt)[g - 3 * NWI - NH0] = make_int4(0, 0, 0, 0);
    } else {
      cvt4(x, xb, g - (3 * NWI + NH0 + NC));
    }
  }
}

// ---------------------------------------------------------------------------
// k_gemm: xp = x @ Wih^T + b_ih, written into d_out. (unchanged, verified)
// ---------------------------------------------------------------------------
template <bool XB>
__global__ __launch_bounds__(256) void k_gemm(const unsigned short* __restrict__ xbg,
                                              const float* __restrict__ xf,
                                              const unsigned short* __restrict__ Wb,
                                              const float* __restrict__ bias,
                                              float* __restrict__ C) {
  __shared__ __align__(16) unsigned short ldsA[128 * 64];
  __shared__ __align__(16) unsigned short ldsB[128 * 64];
  const int tid = threadIdx.x;
  const int w = tid >> 6, l = tid & 63;
  const int lr = l & 15, lk = l >> 4;
  const int n0 = (blockIdx.x & 7) * 128;
  const int m0 = (blockIdx.x >> 3) * 128;
  const int mbase = (w >> 1) * 64, nbase = (w & 1) * 64;

  f32x4 acc[4][4] = {};

  for (int kb = 0; kb < 16; ++kb) {
    const int k0 = kb * 64;
#pragma unroll
    for (int r = 0; r < 4; ++r) {
      int tb = r * 4096 + w * 1024 + l * 16;
      int row = tb >> 7;
      int p = (tb >> 4) & 7;
      int c = p ^ (row & 7);
      gll16(Wb + (u64)(n0 + row) * II_ + k0 + c * 8,
            (char*)ldsB + r * 4096 + w * 1024);
    }
    if constexpr (XB) {
#pragma unroll
      for (int r = 0; r < 4; ++r) {
        int tb = r * 4096 + w * 1024 + l * 16;
        int row = tb >> 7;
        int p = (tb >> 4) & 7;
        int c = p ^ (row & 7);
        gll16(xbg + (u64)(m0 + row) * II_ + k0 + c * 8,
              (char*)ldsA + r * 4096 + w * 1024);
      }
    } else {
      const int r = tid >> 1, ch = tid & 1;
      const float* gs = xf + (u64)(m0 + r) * II_ + k0 + ch * 32;
      float4 v[8];
#pragma unroll
      for (int q = 0; q < 8; ++q) v[q] = ((const float4*)gs)[q];
#pragma unroll
      for (int q = 0; q < 4; ++q) {
        int c = ch * 4 + q;
        int p = c ^ (r & 7);
        uint4 pk;
        pk.x = pk2(v[2 * q].x, v[2 * q].y);
        pk.y = pk2(v[2 * q].z, v[2 * q].w);
        pk.z = pk2(v[2 * q + 1].x, v[2 * q + 1].y);
        pk.w = pk2(v[2 * q + 1].z, v[2 * q + 1].w);
        *(uint4*)((char*)ldsA + r * 128 + p * 16) = pk;
      }
    }
    __syncthreads();

    bf16x8 a[4][2], b[4][2];
#pragma unroll
    for (int mt = 0; mt < 4; ++mt) {
      int row = mbase + mt * 16 + lr;
#pragma unroll
      for (int kk = 0; kk < 2; ++kk) {
        int c = kk * 4 + lk, p = c ^ (row & 7);
        a[mt][kk] = *(const bf16x8*)((const char*)ldsA + row * 128 + p * 16);
      }
    }
#pragma unroll
    for (int nt = 0; nt < 4; ++nt) {
      int row = nbase + nt * 16 + lr;
#pragma unroll
      for (int kk = 0; kk < 2; ++kk) {
        int c = kk * 4 + lk, p = c ^ (row & 7);
        b[nt][kk] = *(const bf16x8*)((const char*)ldsB + row * 128 + p * 16);
      }
    }
#pragma unroll
    for (int kk = 0; kk < 2; ++kk)
#pragma unroll
      for (int mt = 0; mt < 4; ++mt)
#pragma unroll
        for (int nt = 0; nt < 4; ++nt)
          acc[mt][nt] = __builtin_amdgcn_mfma_f32_16x16x32_bf16(a[mt][kk], b[nt][kk], acc[mt][nt], 0, 0, 0);
    __syncthreads();
  }

  float bn[4];
#pragma unroll
  for (int nt = 0; nt < 4; ++nt) bn[nt] = bias[n0 + nbase + nt * 16 + lr];
#pragma unroll
  for (int mt = 0; mt < 4; ++mt) {
#pragma unroll
    for (int i = 0; i < 4; ++i) {
      int m = m0 + mbase + mt * 16 + lk * 4 + i;
      float* cr = C + (u64)m * HH_ + n0 + nbase + lr;
#pragma unroll
      for (int nt = 0; nt < 4; ++nt) cr[nt * 16] = acc[mt][nt][i] + bn[nt];
    }
  }
}

// ---------------------------------------------------------------------------
// k_scan v9 = r2 (best measured: 4.2us/step) surgically de-fattened:
//  (1) weights AGPR-pinned via r4-proven asm MFMA ("a" B-operand) -> no
//      per-step L2 weight re-stream;
//  (2) epilogue remapped to (batch=tid&15, colpair=tid>>4): direct u32
//      h-store + float2 out-store -> hstage transpose, its barrier, and the
//      shfl are gone (combine reads from part[] remap for free);
//  (3) flags padded to 64B (32 LLC lines/domain, parallel slices; r2 had all
//      32 flags in ONE line -> serialized producer stores), flag store
//      RELAXED (explicit vmcnt(0)+barrier already orders h-stores before it),
//      no s_sleep (r2 had none and was fastest).
// Geometry (r2-proven): 128 blocks = 32 j-blocks (32 cols) x 4 domains
// (16 batch rows); 4 waves K-split-256; LDS K-combine (stride-65 pad).
// Protocol (r2-proven): wave0 polls 32 domain flags -> barrier; bulk
// pipelined relaxed-agent u64 h loads; publish = h-store, vmcnt(0), barrier,
// tid0 flag store. Equality flags + double buffer => skew<=1 race-free.
// ---------------------------------------------------------------------------
__global__ __launch_bounds__(256, 1) void k_scan(float* __restrict__ out, const float* __restrict__ h0,
                                                 const float* __restrict__ b1, const float* __restrict__ b2,
                                                 const unsigned short* __restrict__ Wcat,
                                                 unsigned short* __restrict__ hbuf, u32* __restrict__ flags) {
  __shared__ float part[16 * 4 * 65];  // [(w*4+nt)*4+i][l] stride 65 = 16.6KB
  const int tid = threadIdx.x, w = tid >> 6, l = tid & 63;
  const int lr = l & 15, lk = l >> 4;
  const int og = blockIdx.x & 31, bg = blockIdx.x >> 5;
  const int jb = og * 32, bb = bg * 16;
  const int koff = w * 256;

  // --- weights -> 128 AGPRs: nt 0/1 = W_hh1 j-tiles, 2/3 = W_hh2 j-tiles ---
  bf16x8 wt[4][8];
#pragma unroll
  for (int nt = 0; nt < 4; ++nt) {
    int nrow = (nt < 2) ? (jb + nt * 16 + lr) : (HH_ + jb + (nt - 2) * 16 + lr);
    const unsigned short* wr = Wcat + (u64)nrow * HH_ + koff + lk * 8;
#pragma unroll
    for (int kk = 0; kk < 8; ++kk) wt[nt][kk] = *(const bf16x8*)(wr + kk * 32);
  }

  // --- epilogue identity: batch row b = tid&15, col pair jp = tid>>4 ---
  const int b = tid & 15, jp = tid >> 4;
  const int grow = bb + b;
  const int c0 = jb + jp * 2;          // global col of q=0
  float bv1[2] = {b1[c0], b1[c0 + 1]};
  float bv2[2] = {b2[c0], b2[c0 + 1]};
  float hold[2] = {h0[(u64)grow * HH_ + c0], h0[(u64)grow * HH_ + c0 + 1]};
  float* outp = out + (u64)grow * TT_ * HH_ + c0;   // + t*HH_ per step

  u32* dflag = flags + bg * 512;                     // 32 flags, stride 16 u32 (64B)
  const u64 ldw = ((u64)(bb + lr) * HH_ + koff + lk * 8) >> 2;  // u64 idx, h load
  const u64 stw = ((u64)grow * HH_ + c0) >> 1;                  // u32 idx, h store

  for (int t = 0; t < TT_; ++t) {
    float2 xpv = *(const float2*)(outp + (u64)t * HH_);  // xp; hides under poll

    if (t > 0) {
      if (w == 0) {
        const u32 need = (u32)t;
        while (true) {
          u32 v = (l < 32)
                      ? __hip_atomic_load(dflag + l * 16, __ATOMIC_RELAXED, __HIP_MEMORY_SCOPE_AGENT)
                      : 0xFFFFFFFFu;
          if (__all((int)(v >= need))) break;
        }
      }
      __syncthreads();  // also part[] WAR: prior combine reads done
    }

    // --- bulk pipelined h loads (relaxed agent u64 = LLC-direct), MFMA ---
    const u64* hB = (const u64*)hbuf + (u64)(t & 1) * (BB_ * HH_ / 4) + ldw;
    bf16x8 av[8];
#pragma unroll
    for (int kk = 0; kk < 8; ++kk) {
      union { u64 q[2]; bf16x8 v; } au;
      au.q[0] = __hip_atomic_load(hB + kk * 8,     __ATOMIC_RELAXED, __HIP_MEMORY_SCOPE_AGENT);
      au.q[1] = __hip_atomic_load(hB + kk * 8 + 1, __ATOMIC_RELAXED, __HIP_MEMORY_SCOPE_AGENT);
      av[kk] = au.v;
    }

    f32x4 acc[4] = {};
#pragma unroll
    for (int kk = 0; kk < 8; ++kk)
#pragma unroll
      for (int nt = 0; nt < 4; ++nt)
        asm("v_mfma_f32_16x16x32_bf16 %0, %1, %2, %0"
            : "+v"(acc[nt]) : "v"(av[kk]), "a"(wt[nt][kk]));
    // hazard fence: accs pass THROUGH the asm (r8-proven)
    asm volatile("s_nop 7\n\ts_nop 7\n\ts_nop 7"
                 : "+v"(acc[0]), "+v"(acc[1]), "+v"(acc[2]), "+v"(acc[3]));

    // --- K-partials to LDS: D[batch=lk*4+i][j=nt_tile*16+lr] ---
#pragma unroll
    for (int nt = 0; nt < 4; ++nt)
#pragma unroll
      for (int i = 0; i < 4; ++i)
        part[((w * 4 + nt) * 4 + i) * 65 + l] = acc[nt][i];
    __syncthreads();

    // --- combine + gates: thread owns (batch b, cols c0, c0+1) ---
    float hn[2];
#pragma unroll
    for (int q = 0; q < 2; ++q) {
      const int cl = jp * 2 + q;            // local col 0..31
      const int nt1 = cl >> 4, jl = cl & 15;
      const int lidx = (b >> 2) * 16 + jl, ridx = b & 3;
      float v1 = 0.f, v2 = 0.f;
#pragma unroll
      for (int ww = 0; ww < 4; ++ww) {
        v1 += part[((ww * 4 + nt1) * 4 + ridx) * 65 + lidx];
        v2 += part[((ww * 4 + 2 + nt1) * 4 + ridx) * 65 + lidx];
      }
      float xi = (q == 0) ? xpv.x : xpv.y;
      float t1 = tanhfast(v1 + xi + bv1[q]);
      float t2 = tanhfast(v2 + xi + bv2[q]);
      hn[q] = t1 + hold[q] * (t2 - t1);  // (1-h)*v1 + h*v2
      hold[q] = hn[q];
    }

    // --- publish: u32 h-store, vmcnt(0), barrier, tid0 relaxed flag ---
    if (t < TT_ - 1) {
      u32 wd = (u32)bf16rne(hn[0]) | ((u32)bf16rne(hn[1]) << 16);
      __hip_atomic_store((u32*)hbuf + (u64)((t + 1) & 1) * (BB_ * HH_ / 2) + stw, wd,
                         __ATOMIC_RELAXED, __HIP_MEMORY_SCOPE_AGENT);
      asm volatile("s_waitcnt vmcnt(0)" ::: "memory");
      __syncthreads();  // all 256 threads' h-stores are in LLC; part[] WAR
      if (tid == 0)
        __hip_atomic_store(dflag + og * 16, (u32)(t + 1), __ATOMIC_RELAXED, __HIP_MEMORY_SCOPE_AGENT);
    } else {
      *(float2*)(out + (u64)BB_ * TT_ * HH_ + (u64)grow * HH_ + c0) = make_float2(hn[0], hn[1]);
    }

    // --- fp32 trajectory store AFTER the handshake (off critical chain) ---
    *(float2*)(outp + (u64)t * HH_) = make_float2(hn[0], hn[1]);
  }
}

// ---------------------------------------------------------------------------
extern "C" void kernel_launch(void* const* d_in, const int* in_sizes, int n_in,
                              void* d_out, int out_size, void* d_ws, size_t ws_size,
                              hipStream_t stream) {
  const float* x    = (const float*)d_in[0];
  const float* h0   = (const float*)d_in[1];
  const float* Wih  = (const float*)d_in[2];
  const float* bih  = (const float*)d_in[3];
  const float* Whh1 = (const float*)d_in[4];
  const float* bhh1 = (const float*)d_in[5];
  const float* Whh2 = (const float*)d_in[6];
  const float* bhh2 = (const float*)d_in[7];
  float* out = (float*)d_out;

  char* ws = (char*)d_ws;
  unsigned short* Wihb  = (unsigned short*)(ws + 0);          //  2 MiB
  unsigned short* Wcatb = (unsigned short*)(ws + 2097152);    //  4 MiB
  unsigned short* hbuf  = (unsigned short*)(ws + 6291456);    //  256 KiB (2 bf16 buffers)
  int*            cnt   = (int*)(ws + 6553600);               //  16 KiB (padded flags)
  unsigned short* xb    = (unsigned short*)(ws + 6569984);    //  64 MiB
  const bool fastx = ws_size >= 73678848ULL;

  hipLaunchKernelGGL(k_convert, dim3(2048), dim3(256), 0, stream,
                     x, h0, Wih, Whh1, Whh2, xb, Wihb, Wcatb, hbuf, cnt, (int)fastx);
  if (fastx)
    hipLaunchKernelGGL((k_gemm<true>), dim3(2048), dim3(256), 0, stream,
                       xb, (const float*)nullptr, Wihb, bih, out);
  else
    hipLaunchKernelGGL((k_gemm<false>), dim3(2048), dim3(256), 0, stream,
                       (const unsigned short*)nullptr, x, Wihb, bih, out);
  hipLaunchKernelGGL(k_scan, dim3(NSCAN_BLOCKS), dim3(256), 0, stream,
                     out, h0, bhh1, bhh2, Wcatb, hbuf, (u32*)cnt);
}